// Round 4
// baseline (985.329 us; speedup 1.0000x reference)
//
#include <hip/hip_runtime.h>
#include <math.h>

#define HH 2048
#define WW 2048
#define PLANE 4194304        // HH*WW
#define TPITCH 44
#define TPP (26*TPITCH)      // 1144 floats per plane

// ws layout (bytes):
// 0     : float gwin[11]
// 64    : float gwin3[11]
// 128   : double lG[4]
// 256   : double lYpart[4*528]   (16896 B)
// 17408 : double qpart[8192]     (65536 B)

__device__ inline double wave_red(double v) {
#pragma unroll
  for (int o = 32; o > 0; o >>= 1) v += __shfl_down(v, o, 64);
  return v;
}

__global__ void k0_window(float* gwin, float* gwin3) {
  if (threadIdx.x == 0) {
    double e[11], s = 0.0;
    double sig = 11.0 / 6.0;
    for (int i = 0; i < 11; ++i) {
      double x = (double)(i - 5);
      e[i] = exp(-(x * x) / (2.0 * sig * sig));
      s += e[i];
    }
    for (int i = 0; i < 11; ++i) {
      gwin[i]  = (float)(e[i] / s);
      gwin3[i] = (float)(e[i] / (3.0 * s));
    }
  }
}

// k1: lY partial sums (unchanged from round 3; ~18 us).
__global__ __launch_bounds__(256) void k1_lY(const float* __restrict__ Ys,
                                             const float* __restrict__ gwin,
                                             double* __restrict__ lYpart) {
  int bid = blockIdx.x;
  int tid = threadIdx.x;
  double acc = 0.0;
  __shared__ float P[12];
  __shared__ double red[4];

  if (bid < 2048) {
    const float4* __restrict__ p = (const float4*)Ys;
    int base = bid * 6144 + tid;
#pragma unroll 1
    for (int gblk = 0; gblk < 3; ++gblk) {
      float ax = 0.f, ay = 0.f;
#pragma unroll
      for (int u = 0; u < 8; ++u) {
        float4 v = p[base + (gblk * 8 + u) * 256];
        ax += v.x + v.z;
        ay += v.y + v.w;
      }
      acc += (double)(ax + ay);
    }
  } else {
    int b = bid - 2048;             // 0..63
    int k = b >> 4, sub = b & 15;
    if (tid == 0) {
      float s = 0.f;
      for (int i = 0; i < 12; ++i) { P[i] = s; if (i < 11) s += gwin[i]; }
    }
    __syncthreads();
    const float4* __restrict__ Yk4 = (const float4*)(Ys + (size_t)k * 3 * PLANE);
    auto covP = [&](int r) -> float {
      if (r >= 5 && r <= 2042) return 1.0f;
      int dhi = r + 5; if (dhi > 10) dhi = 10;
      int dlo = r - 2042; if (dlo < 0) dlo = 0;
      return P[dhi + 1] - P[dlo];
    };
#pragma unroll 1
    for (int t = sub * 256 + tid; t < 39816; t += 4096) {
      int ch, row, g4;
      if (t < 15360) {
        ch = t / 5120;
        int r = (t % 5120) / 512;
        g4 = t & 511;
        row = (r < 5) ? r : r + 2038;
      } else {
        int u = t - 15360;
        ch = u / 8152;
        int rem = u % 8152;
        row = 5 + (rem >> 2);
        int gi = rem & 3;
        g4 = (gi < 2) ? gi : 508 + gi;
      }
      float4 v = Yk4[ch * 1048576 + row * 512 + g4];
      float cy = covP(row);
      int x0 = g4 << 2;
      float w0 = cy * covP(x0)     - 1.0f;
      float w1 = cy * covP(x0 + 1) - 1.0f;
      float w2 = cy * covP(x0 + 2) - 1.0f;
      float w3 = cy * covP(x0 + 3) - 1.0f;
      acc += (double)(w0 * v.x + w1 * v.y + w2 * v.z + w3 * v.w);
    }
  }

  acc = wave_red(acc);
  int lane = tid & 63, wid = tid >> 6;
  __syncthreads();
  if (lane == 0) red[wid] = acc;
  __syncthreads();
  if (tid == 0) {
    double tot = red[0] + red[1] + red[2] + red[3];
    if (bid < 2048) {
      int k = bid >> 9;
      lYpart[k * 528 + (bid & 511)] = tot;
    } else {
      int b = bid - 2048;
      lYpart[(b >> 4) * 528 + 512 + (b & 15)] = tot;
    }
  }
}

__global__ __launch_bounds__(256) void k2a_lG(const double* __restrict__ lYpart,
                                              double* __restrict__ lG) {
  __shared__ double red[4];
  for (int k = 0; k < 4; ++k) {
    const double* p = lYpart + k * 528;
    double v = p[threadIdx.x] + p[256 + threadIdx.x];
    if (threadIdx.x < 16) v += p[512 + threadIdx.x];
    v = wave_red(v);
    int lane = threadIdx.x & 63, wid = threadIdx.x >> 6;
    if (lane == 0) red[wid] = v;
    __syncthreads();
    if (threadIdx.x == 0) {
      double tot = red[0] + red[1] + red[2] + red[3];
      double lY = tot * (1.0 / 12582912.0);
      double d = lY - 0.5;
      lG[k] = exp(-(d * d) / 0.08);
    }
    __syncthreads();
  }
}

// k2 v4: 32x16 tile, phase-split over {X, k=0..3}. 6 small LDS planes
// (0-2 products, 3-5 H-blurred), per-pixel state in registers across phases.
// 27.5 KB LDS -> 4 blocks/CU target (100% occupancy).
__global__ __launch_bounds__(512, 8) void k2_main(const float* __restrict__ X,
                                                  const float* __restrict__ Ys,
                                                  const float* __restrict__ gwin,
                                                  const float* __restrict__ gwin3,
                                                  const double* __restrict__ lG,
                                                  double* __restrict__ qpart) {
  __shared__ float4 lds4[6 * TPP / 4];     // 6864 floats = 27456 B
  __shared__ double qred[8];
  float* lds = (float*)lds4;

  int bid = blockIdx.x;
  int wg = (bid & 7) * 1024 + (bid >> 3);  // XCD-compact swizzle
  int tX = wg & 63, tY = wg >> 6;
  int x0 = tX * 32, y0 = tY * 16;
  int tid = threadIdx.x;

  float g[11], g3[11];
#pragma unroll
  for (int i = 0; i < 11; ++i) { g[i] = gwin[i]; g3[i] = gwin3[i]; }

  // ---- per-thread A-task geometry (tid < 286) ----
  int arow = tid / 11, ag = tid - arow * 11;
  int agy = y0 - 5 + arow;
  int agx = x0 - 6 + 4 * ag;
  bool arok = (tid < 286) && ((unsigned)agy < (unsigned)HH);
  size_t arbase = arok ? (size_t)agy * WW : 0;
  int aob = arow * TPITCH + 4 * ag;

  auto ld4 = [&](const float* src) -> float4 {
    float4 r = make_float4(0.f, 0.f, 0.f, 0.f);
    if (arok) {
      int xx = agx;
      if ((unsigned)xx < (unsigned)WW) {
        float2 t = *(const float2*)(src + arbase + xx);
        r.x = t.x; r.y = t.y;
      }
      xx = agx + 2;
      if ((unsigned)xx < (unsigned)WW) {
        float2 t = *(const float2*)(src + arbase + xx);
        r.z = t.x; r.w = t.y;
      }
    }
    return r;
  };

  // ---- per-pixel persistent state ----
  int dty = tid >> 5, dtx = tid & 31;
  int doff = dty * TPITCH + 6 + dtx;
  float muX = 0.f, sigX = 0.f;
  float best_sig = -1e30f, best_cs = 0.f;
  float num = 0.f, den = 0.f;

  // ================= phase X: Sx, Sx2 =================
  if (tid < 286) {
    float4 a0 = ld4(X), a1 = ld4(X + PLANE), a2 = ld4(X + 2 * PLANE);
    float4 sx, sx2;
#pragma unroll
    for (int e = 0; e < 4; ++e) {
      float v0 = ((float*)&a0)[e], v1 = ((float*)&a1)[e], v2 = ((float*)&a2)[e];
      ((float*)&sx)[e]  = v0 + v1 + v2;
      ((float*)&sx2)[e] = v0 * v0 + v1 * v1 + v2 * v2;
    }
    *(float4*)(lds + 0 * TPP + aob) = sx;
    *(float4*)(lds + 1 * TPP + aob) = sx2;
  }
  __syncthreads();

  // H-blur: planes {0,1} -> {3,4}
  if (tid < 52) {
    int p = tid / 26, r = tid - p * 26;
    const float* ip = lds + p * TPP + r * TPITCH;
    float* op = lds + (3 + p) * TPP + r * TPITCH;
    float w[44];
#pragma unroll
    for (int j = 0; j < 11; ++j) {
      float4 w4 = *(const float4*)(ip + 4 * j);
      w[4*j] = w4.x; w[4*j+1] = w4.y; w[4*j+2] = w4.z; w[4*j+3] = w4.w;
    }
#pragma unroll
    for (int gq = 0; gq < 9; ++gq) {
      float4 o4;
#pragma unroll
      for (int e = 0; e < 4; ++e) {
        int pp = 4 * gq + e;
        float s = 0.f;
#pragma unroll
        for (int d = 0; d < 11; ++d) {
          int wi = pp - 1 + d;
          if (wi < 0) wi = 0;
          if (wi > 43) wi = 43;
          s += g[d] * w[wi];
        }
        ((float*)&o4)[e] = s;
      }
      *(float4*)(op + 4 + 4 * gq) = o4;
    }
  }
  __syncthreads();

  // V-blur: planes {3,4} -> {0,1} (rows 0..15)
  if (tid < 36) {
    int p = tid / 18, rr = tid - p * 18;
    int ccg = 1 + (rr >> 1), half = rr & 1;
    const float* cp = lds + (3 + p) * TPP + (half * 8) * TPITCH + ccg * 4;
    float* wp = lds + p * TPP + (half * 8) * TPITCH + ccg * 4;
    float4 acc[8];
#pragma unroll
    for (int i = 0; i < 8; ++i) acc[i] = make_float4(0.f, 0.f, 0.f, 0.f);
#pragma unroll
    for (int j = 0; j < 18; ++j) {
      float4 vv = *(const float4*)(cp + j * TPITCH);
#pragma unroll
      for (int r2 = 0; r2 < 8; ++r2) {
        int d = j - r2;
        if (d >= 0 && d < 11) {
          acc[r2].x += g3[d] * vv.x;
          acc[r2].y += g3[d] * vv.y;
          acc[r2].z += g3[d] * vv.z;
          acc[r2].w += g3[d] * vv.w;
        }
      }
    }
#pragma unroll
    for (int r2 = 0; r2 < 8; ++r2)
      *(float4*)(wp + r2 * TPITCH) = acc[r2];
  }
  __syncthreads();

  muX = lds[0 * TPP + doff];
  sigX = lds[1 * TPP + doff] - muX * muX;
  __syncthreads();

  // ================= phases k = 0..3 =================
#pragma unroll 1
  for (int k = 0; k < 4; ++k) {
    const float* Yk = Ys + (size_t)k * 3 * PLANE;
    float lGk = (float)lG[k];

    if (tid < 286) {
      float4 a0 = ld4(X), a1 = ld4(X + PLANE), a2 = ld4(X + 2 * PLANE);
      float4 b0 = ld4(Yk), b1 = ld4(Yk + PLANE), b2 = ld4(Yk + 2 * PLANE);
      float4 sy, sy2, sxy;
#pragma unroll
      for (int e = 0; e < 4; ++e) {
        float xa = ((float*)&a0)[e], xb = ((float*)&a1)[e], xc = ((float*)&a2)[e];
        float ya = ((float*)&b0)[e], yb = ((float*)&b1)[e], yc = ((float*)&b2)[e];
        ((float*)&sy)[e]  = ya + yb + yc;
        ((float*)&sy2)[e] = ya * ya + yb * yb + yc * yc;
        ((float*)&sxy)[e] = xa * ya + xb * yb + xc * yc;
      }
      *(float4*)(lds + 0 * TPP + aob) = sy;
      *(float4*)(lds + 1 * TPP + aob) = sy2;
      *(float4*)(lds + 2 * TPP + aob) = sxy;
    }
    __syncthreads();

    // H-blur: planes {0,1,2} -> {3,4,5}
    if (tid < 78) {
      int p = tid / 26, r = tid - p * 26;
      const float* ip = lds + p * TPP + r * TPITCH;
      float* op = lds + (3 + p) * TPP + r * TPITCH;
      float w[44];
#pragma unroll
      for (int j = 0; j < 11; ++j) {
        float4 w4 = *(const float4*)(ip + 4 * j);
        w[4*j] = w4.x; w[4*j+1] = w4.y; w[4*j+2] = w4.z; w[4*j+3] = w4.w;
      }
#pragma unroll
      for (int gq = 0; gq < 9; ++gq) {
        float4 o4;
#pragma unroll
        for (int e = 0; e < 4; ++e) {
          int pp = 4 * gq + e;
          float s = 0.f;
#pragma unroll
          for (int d = 0; d < 11; ++d) {
            int wi = pp - 1 + d;
            if (wi < 0) wi = 0;
            if (wi > 43) wi = 43;
            s += g[d] * w[wi];
          }
          ((float*)&o4)[e] = s;
        }
        *(float4*)(op + 4 + 4 * gq) = o4;
      }
    }
    __syncthreads();

    // V-blur: planes {3,4,5} -> {0,1,2} (rows 0..15)
    if (tid < 54) {
      int p = tid / 18, rr = tid - p * 18;
      int ccg = 1 + (rr >> 1), half = rr & 1;
      const float* cp = lds + (3 + p) * TPP + (half * 8) * TPITCH + ccg * 4;
      float* wp = lds + p * TPP + (half * 8) * TPITCH + ccg * 4;
      float4 acc[8];
#pragma unroll
      for (int i = 0; i < 8; ++i) acc[i] = make_float4(0.f, 0.f, 0.f, 0.f);
#pragma unroll
      for (int j = 0; j < 18; ++j) {
        float4 vv = *(const float4*)(cp + j * TPITCH);
#pragma unroll
        for (int r2 = 0; r2 < 8; ++r2) {
          int d = j - r2;
          if (d >= 0 && d < 11) {
            acc[r2].x += g3[d] * vv.x;
            acc[r2].y += g3[d] * vv.y;
            acc[r2].z += g3[d] * vv.z;
            acc[r2].w += g3[d] * vv.w;
          }
        }
      }
#pragma unroll
      for (int r2 = 0; r2 < 8; ++r2)
        *(float4*)(wp + r2 * TPITCH) = acc[r2];
    }
    __syncthreads();

    // fusion update for this k
    {
      float muY  = lds[0 * TPP + doff];
      float sigY = lds[1 * TPP + doff] - muY * muY;
      float sXY  = lds[2 * TPP + doff] - muX * muY;
      float cs = (2.f * sXY + 9e-4f) / (sigX + sigY + 9e-4f);
      if (sigY > best_sig) { best_sig = sigY; best_cs = cs; }
      float dm = muY - 0.5f;
      float lL = expf(-dm * dm * 12.5f);
      float LY = lGk * lL;
      num += LY * muY;
      den += LY;
    }
    __syncthreads();
  }

  // ---- finalize ----
  {
    float muYw = num / den;
    float l = (2.f * muX * muYw + 1e-4f) / (muX * muX + muYw * muYw + 1e-4f);
    double v = (double)(l * best_cs);
    v = wave_red(v);
    int lane = tid & 63, wid = tid >> 6;
    if (lane == 0) qred[wid] = v;
    __syncthreads();
    if (tid == 0) {
      double t = 0.0;
#pragma unroll
      for (int i = 0; i < 8; ++i) t += qred[i];
      qpart[blockIdx.x] = t;
    }
  }
}

__global__ __launch_bounds__(512) void k3_final(const double* __restrict__ qpart,
                                                float* __restrict__ out) {
  double acc = 0.0;
  for (int i = threadIdx.x; i < 8192; i += 512) acc += qpart[i];
  acc = wave_red(acc);
  __shared__ double red[8];
  int lane = threadIdx.x & 63, wid = threadIdx.x >> 6;
  if (lane == 0) red[wid] = acc;
  __syncthreads();
  if (threadIdx.x == 0)
    out[0] = (float)((red[0] + red[1] + red[2] + red[3] +
                      red[4] + red[5] + red[6] + red[7]) * (1.0 / 4194304.0));
}

extern "C" void kernel_launch(void* const* d_in, const int* in_sizes, int n_in,
                              void* d_out, int out_size, void* d_ws, size_t ws_size,
                              hipStream_t stream) {
  const float* X  = (const float*)d_in[0];
  const float* Ys = (const float*)d_in[1];
  char* ws = (char*)d_ws;
  float*  gwin   = (float*)(ws + 0);
  float*  gwin3  = (float*)(ws + 64);
  double* lG     = (double*)(ws + 128);
  double* lYpart = (double*)(ws + 256);
  double* qpart  = (double*)(ws + 17408);
  float* out = (float*)d_out;

  hipLaunchKernelGGL(k0_window, dim3(1), dim3(64), 0, stream, gwin, gwin3);
  hipLaunchKernelGGL(k1_lY, dim3(2112), dim3(256), 0, stream, Ys, gwin, lYpart);
  hipLaunchKernelGGL(k2a_lG, dim3(1), dim3(256), 0, stream, lYpart, lG);
  hipLaunchKernelGGL(k2_main, dim3(8192), dim3(512), 0, stream, X, Ys, gwin, gwin3, lG, qpart);
  hipLaunchKernelGGL(k3_final, dim3(1), dim3(512), 0, stream, qpart, out);
}

// Round 5
// 186.299 us; speedup vs baseline: 5.2890x; 5.2890x over previous
//
#include <hip/hip_runtime.h>
#include <math.h>

#define HH 2048
#define WW 2048
#define PLANE 4194304        // HH*WW
#define TPITCH 44
#define TPP (26*TPITCH)      // 1144 floats per plane

// ws layout (bytes):
// 0     : float gwin[11]
// 64    : float gwin3[11]
// 128   : double lG[4]
// 256   : double lYpart[4*528]   (16896 B)
// 17408 : double qpart[8192]     (65536 B)

__device__ inline double wave_red(double v) {
#pragma unroll
  for (int o = 32; o > 0; o >>= 1) v += __shfl_down(v, o, 64);
  return v;
}

__global__ void k0_window(float* gwin, float* gwin3) {
  if (threadIdx.x == 0) {
    double e[11], s = 0.0;
    double sig = 11.0 / 6.0;
    for (int i = 0; i < 11; ++i) {
      double x = (double)(i - 5);
      e[i] = exp(-(x * x) / (2.0 * sig * sig));
      s += e[i];
    }
    for (int i = 0; i < 11; ++i) {
      gwin[i]  = (float)(e[i] / s);
      gwin3[i] = (float)(e[i] / (3.0 * s));
    }
  }
}

// k1: lY partial sums (unchanged; ~18 us).
__global__ __launch_bounds__(256) void k1_lY(const float* __restrict__ Ys,
                                             const float* __restrict__ gwin,
                                             double* __restrict__ lYpart) {
  int bid = blockIdx.x;
  int tid = threadIdx.x;
  double acc = 0.0;
  __shared__ float P[12];
  __shared__ double red[4];

  if (bid < 2048) {
    const float4* __restrict__ p = (const float4*)Ys;
    int base = bid * 6144 + tid;
#pragma unroll 1
    for (int gblk = 0; gblk < 3; ++gblk) {
      float ax = 0.f, ay = 0.f;
#pragma unroll
      for (int u = 0; u < 8; ++u) {
        float4 v = p[base + (gblk * 8 + u) * 256];
        ax += v.x + v.z;
        ay += v.y + v.w;
      }
      acc += (double)(ax + ay);
    }
  } else {
    int b = bid - 2048;             // 0..63
    int k = b >> 4, sub = b & 15;
    if (tid == 0) {
      float s = 0.f;
      for (int i = 0; i < 12; ++i) { P[i] = s; if (i < 11) s += gwin[i]; }
    }
    __syncthreads();
    const float4* __restrict__ Yk4 = (const float4*)(Ys + (size_t)k * 3 * PLANE);
    auto covP = [&](int r) -> float {
      if (r >= 5 && r <= 2042) return 1.0f;
      int dhi = r + 5; if (dhi > 10) dhi = 10;
      int dlo = r - 2042; if (dlo < 0) dlo = 0;
      return P[dhi + 1] - P[dlo];
    };
#pragma unroll 1
    for (int t = sub * 256 + tid; t < 39816; t += 4096) {
      int ch, row, g4;
      if (t < 15360) {
        ch = t / 5120;
        int r = (t % 5120) / 512;
        g4 = t & 511;
        row = (r < 5) ? r : r + 2038;
      } else {
        int u = t - 15360;
        ch = u / 8152;
        int rem = u % 8152;
        row = 5 + (rem >> 2);
        int gi = rem & 3;
        g4 = (gi < 2) ? gi : 508 + gi;
      }
      float4 v = Yk4[ch * 1048576 + row * 512 + g4];
      float cy = covP(row);
      int x0 = g4 << 2;
      float w0 = cy * covP(x0)     - 1.0f;
      float w1 = cy * covP(x0 + 1) - 1.0f;
      float w2 = cy * covP(x0 + 2) - 1.0f;
      float w3 = cy * covP(x0 + 3) - 1.0f;
      acc += (double)(w0 * v.x + w1 * v.y + w2 * v.z + w3 * v.w);
    }
  }

  acc = wave_red(acc);
  int lane = tid & 63, wid = tid >> 6;
  __syncthreads();
  if (lane == 0) red[wid] = acc;
  __syncthreads();
  if (tid == 0) {
    double tot = red[0] + red[1] + red[2] + red[3];
    if (bid < 2048) {
      int k = bid >> 9;
      lYpart[k * 528 + (bid & 511)] = tot;
    } else {
      int b = bid - 2048;
      lYpart[(b >> 4) * 528 + 512 + (b & 15)] = tot;
    }
  }
}

__global__ __launch_bounds__(256) void k2a_lG(const double* __restrict__ lYpart,
                                              double* __restrict__ lG) {
  __shared__ double red[4];
  for (int k = 0; k < 4; ++k) {
    const double* p = lYpart + k * 528;
    double v = p[threadIdx.x] + p[256 + threadIdx.x];
    if (threadIdx.x < 16) v += p[512 + threadIdx.x];
    v = wave_red(v);
    int lane = threadIdx.x & 63, wid = threadIdx.x >> 6;
    if (lane == 0) red[wid] = v;
    __syncthreads();
    if (threadIdx.x == 0) {
      double tot = red[0] + red[1] + red[2] + red[3];
      double lY = tot * (1.0 / 12582912.0);
      double d = lY - 0.5;
      lG[k] = exp(-(d * d) / 0.08);
    }
    __syncthreads();
  }
}

// ---- templated blur stages (r3-proven bodies, plane count NP) ----
template <int NP>
__device__ inline void hblur_planes(float* lds, int tid, const float* g) {
  if (tid < NP * 26) {
    int f = tid / 26, row = tid - f * 26;
    float* rp = lds + f * TPP + row * TPITCH;
    float w[44];
#pragma unroll
    for (int j = 0; j < 11; ++j) {
      float4 w4 = *(const float4*)(rp + 4 * j);
      w[4*j] = w4.x; w[4*j+1] = w4.y; w[4*j+2] = w4.z; w[4*j+3] = w4.w;
    }
#pragma unroll
    for (int gq = 0; gq < 9; ++gq) {
      float4 o4;
#pragma unroll
      for (int e = 0; e < 4; ++e) {
        int pp = 4 * gq + e;
        float s = 0.f;
#pragma unroll
        for (int d = 0; d < 11; ++d) {
          int wi = pp - 1 + d;
          if (wi < 0) wi = 0;
          if (wi > 43) wi = 43;
          s += g[d] * w[wi];
        }
        ((float*)&o4)[e] = s;
      }
      *(float4*)(rp + 4 + 4 * gq) = o4;
    }
  }
}

// V-blur planes in place (rows 0..15 written), reg-buffered.
// ALL threads must call (internal barrier).
template <int NP>
__device__ inline void vblur_planes(float* lds, int tid, const float* g3) {
  float4 acc[8];
  bool valid = tid < NP * 18;
  int f = 0, ccg = 0, half = 0;
  if (valid) {
    f = tid / 18;
    int rr = tid - f * 18;
    ccg = 1 + (rr >> 1);
    half = rr & 1;
    const float* cp = lds + f * TPP + (half * 8) * TPITCH + ccg * 4;
#pragma unroll
    for (int i = 0; i < 8; ++i) acc[i] = make_float4(0.f, 0.f, 0.f, 0.f);
#pragma unroll
    for (int j = 0; j < 18; ++j) {
      float4 vv = *(const float4*)(cp + j * TPITCH);
#pragma unroll
      for (int r2 = 0; r2 < 8; ++r2) {
        int d = j - r2;
        if (d >= 0 && d < 11) {
          acc[r2].x += g3[d] * vv.x;
          acc[r2].y += g3[d] * vv.y;
          acc[r2].z += g3[d] * vv.z;
          acc[r2].w += g3[d] * vv.w;
        }
      }
    }
  }
  __syncthreads();
  if (valid) {
    float* wp = lds + f * TPP + (half * 8) * TPITCH + ccg * 4;
#pragma unroll
    for (int r2 = 0; r2 < 8; ++r2)
      *(float4*)(wp + r2 * TPITCH) = acc[r2];
  }
}

// k2 v5: 32x16 tile, TWO passes over an 8-plane LDS buffer (36.6 KB).
// Pass 1: {Sx,Sx2} + k0,k1 (reads X,Y0,Y1). Pass 2: k2,k3 (reads Y2,Y3;
// X held in registers). Total global plane-reads = 15 (same as r3).
__global__ __launch_bounds__(512, 6) void k2_main(const float* __restrict__ X,
                                                  const float* __restrict__ Ys,
                                                  const float* __restrict__ gwin,
                                                  const float* __restrict__ gwin3,
                                                  const double* __restrict__ lG,
                                                  double* __restrict__ qpart) {
  __shared__ float4 lds4[8 * TPP / 4];     // 9152 floats = 36608 B
  __shared__ double qred[8];
  float* lds = (float*)lds4;

  int bid = blockIdx.x;
  int wg = (bid & 7) * 1024 + (bid >> 3);  // XCD-compact swizzle
  int tX = wg & 63, tY = wg >> 6;
  int x0 = tX * 32, y0 = tY * 16;
  int tid = threadIdx.x;

  float g[11], g3[11];
#pragma unroll
  for (int i = 0; i < 11; ++i) { g[i] = gwin[i]; g3[i] = gwin3[i]; }

  // ---- A-task geometry (tid < 286) ----
  int arow = tid / 11, ag = tid - arow * 11;
  int agy = y0 - 5 + arow;
  int agx = x0 - 6 + 4 * ag;
  bool aactive = tid < 286;
  bool arok = aactive && ((unsigned)agy < (unsigned)HH);
  size_t arbase = arok ? (size_t)agy * WW : 0;
  int aob = arow * TPITCH + 4 * ag;

  auto ld4 = [&](const float* src) -> float4 {
    float4 r = make_float4(0.f, 0.f, 0.f, 0.f);
    if (arok) {
      int xx = agx;
      if ((unsigned)xx < (unsigned)WW) {
        float2 t = *(const float2*)(src + arbase + xx);
        r.x = t.x; r.y = t.y;
      }
      xx = agx + 2;
      if ((unsigned)xx < (unsigned)WW) {
        float2 t = *(const float2*)(src + arbase + xx);
        r.z = t.x; r.w = t.y;
      }
    }
    return r;
  };

  // per-pixel persistent fusion state
  int dty = tid >> 5, dtx = tid & 31;
  int doff = dty * TPITCH + 6 + dtx;
  float muX = 0.f, sigX = 0.f;
  float best_sig = -1e30f, best_cs = 0.f;
  float num = 0.f, den = 0.f;

  // X held in registers across both passes (A-threads only)
  float4 xa0, xa1, xa2;

  // writes product triple {Sy,Sy2,Sxy} for one exposure at plane base pb
  auto write_k_products = [&](const float4& b0, const float4& b1,
                              const float4& b2, int pb) {
    float4 sy, sy2, sxy;
#pragma unroll
    for (int e = 0; e < 4; ++e) {
      float xA = ((const float*)&xa0)[e], xB = ((const float*)&xa1)[e],
            xC = ((const float*)&xa2)[e];
      float ya = ((const float*)&b0)[e], yb = ((const float*)&b1)[e],
            yc = ((const float*)&b2)[e];
      ((float*)&sy)[e]  = ya + yb + yc;
      ((float*)&sy2)[e] = ya * ya + yb * yb + yc * yc;
      ((float*)&sxy)[e] = xA * ya + xB * yb + xC * yc;
    }
    *(float4*)(lds + (pb + 0) * TPP + aob) = sy;
    *(float4*)(lds + (pb + 1) * TPP + aob) = sy2;
    *(float4*)(lds + (pb + 2) * TPP + aob) = sxy;
  };

  // fusion update for one exposure k with blurred planes at base pb
  auto fuse_k = [&](int k, int pb) {
    float muY  = lds[(pb + 0) * TPP + doff];
    float sigY = lds[(pb + 1) * TPP + doff] - muY * muY;
    float sXY  = lds[(pb + 2) * TPP + doff] - muX * muY;
    float cs = (2.f * sXY + 9e-4f) / (sigX + sigY + 9e-4f);
    if (sigY > best_sig) { best_sig = sigY; best_cs = cs; }
    float dm = muY - 0.5f;
    float lL = expf(-dm * dm * 12.5f);
    float LY = (float)lG[k] * lL;
    num += LY * muY;
    den += LY;
  };

  // ================= pass 1: Sx, Sx2, k0, k1 =================
  if (aactive) {
    xa0 = ld4(X); xa1 = ld4(X + PLANE); xa2 = ld4(X + 2 * PLANE);
    float4 sx, sx2;
#pragma unroll
    for (int e = 0; e < 4; ++e) {
      float v0 = ((float*)&xa0)[e], v1 = ((float*)&xa1)[e], v2 = ((float*)&xa2)[e];
      ((float*)&sx)[e]  = v0 + v1 + v2;
      ((float*)&sx2)[e] = v0 * v0 + v1 * v1 + v2 * v2;
    }
    *(float4*)(lds + 0 * TPP + aob) = sx;
    *(float4*)(lds + 1 * TPP + aob) = sx2;
    {
      const float* Y0 = Ys;
      float4 b0 = ld4(Y0), b1 = ld4(Y0 + PLANE), b2 = ld4(Y0 + 2 * PLANE);
      write_k_products(b0, b1, b2, 2);
    }
    {
      const float* Y1 = Ys + (size_t)3 * PLANE;
      float4 b0 = ld4(Y1), b1 = ld4(Y1 + PLANE), b2 = ld4(Y1 + 2 * PLANE);
      write_k_products(b0, b1, b2, 5);
    }
  }
  __syncthreads();
  hblur_planes<8>(lds, tid, g);
  __syncthreads();
  vblur_planes<8>(lds, tid, g3);
  __syncthreads();
  muX  = lds[0 * TPP + doff];
  sigX = lds[1 * TPP + doff] - muX * muX;
  fuse_k(0, 2);
  fuse_k(1, 5);
  __syncthreads();

  // ================= pass 2: k2, k3 =================
  if (aactive) {
    {
      const float* Y2 = Ys + (size_t)6 * PLANE;
      float4 b0 = ld4(Y2), b1 = ld4(Y2 + PLANE), b2 = ld4(Y2 + 2 * PLANE);
      write_k_products(b0, b1, b2, 0);
    }
    {
      const float* Y3 = Ys + (size_t)9 * PLANE;
      float4 b0 = ld4(Y3), b1 = ld4(Y3 + PLANE), b2 = ld4(Y3 + 2 * PLANE);
      write_k_products(b0, b1, b2, 3);
    }
  }
  __syncthreads();
  hblur_planes<6>(lds, tid, g);
  __syncthreads();
  vblur_planes<6>(lds, tid, g3);
  __syncthreads();
  fuse_k(2, 0);
  fuse_k(3, 3);

  // ---- finalize ----
  {
    float muYw = num / den;
    float l = (2.f * muX * muYw + 1e-4f) / (muX * muX + muYw * muYw + 1e-4f);
    double v = (double)(l * best_cs);
    v = wave_red(v);
    int lane = tid & 63, wid = tid >> 6;
    if (lane == 0) qred[wid] = v;
    __syncthreads();
    if (tid == 0) {
      double t = 0.0;
#pragma unroll
      for (int i = 0; i < 8; ++i) t += qred[i];
      qpart[blockIdx.x] = t;
    }
  }
}

__global__ __launch_bounds__(512) void k3_final(const double* __restrict__ qpart,
                                                float* __restrict__ out) {
  double acc = 0.0;
  for (int i = threadIdx.x; i < 8192; i += 512) acc += qpart[i];
  acc = wave_red(acc);
  __shared__ double red[8];
  int lane = threadIdx.x & 63, wid = threadIdx.x >> 6;
  if (lane == 0) red[wid] = acc;
  __syncthreads();
  if (threadIdx.x == 0)
    out[0] = (float)((red[0] + red[1] + red[2] + red[3] +
                      red[4] + red[5] + red[6] + red[7]) * (1.0 / 4194304.0));
}

extern "C" void kernel_launch(void* const* d_in, const int* in_sizes, int n_in,
                              void* d_out, int out_size, void* d_ws, size_t ws_size,
                              hipStream_t stream) {
  const float* X  = (const float*)d_in[0];
  const float* Ys = (const float*)d_in[1];
  char* ws = (char*)d_ws;
  float*  gwin   = (float*)(ws + 0);
  float*  gwin3  = (float*)(ws + 64);
  double* lG     = (double*)(ws + 128);
  double* lYpart = (double*)(ws + 256);
  double* qpart  = (double*)(ws + 17408);
  float* out = (float*)d_out;

  hipLaunchKernelGGL(k0_window, dim3(1), dim3(64), 0, stream, gwin, gwin3);
  hipLaunchKernelGGL(k1_lY, dim3(2112), dim3(256), 0, stream, Ys, gwin, lYpart);
  hipLaunchKernelGGL(k2a_lG, dim3(1), dim3(256), 0, stream, lYpart, lG);
  hipLaunchKernelGGL(k2_main, dim3(8192), dim3(512), 0, stream, X, Ys, gwin, gwin3, lG, qpart);
  hipLaunchKernelGGL(k3_final, dim3(1), dim3(512), 0, stream, qpart, out);
}